// Round 9
// baseline (98.556 us; speedup 1.0000x reference)
//
#include <hip/hip_runtime.h>
#include <math.h>

#define B_ 32
#define T_ 512
#define D_ 256
#define TP_ 514              // padded T: one zero row each side
#define KTOT 768             // 3 taps x 256 channels
#define NSTEP 24             // KTOT / 32
#define TILE_M 64
#define BUFSZ 20480          // A 4KB + B 16KB
#define GROWS 32             // gather rows per merged-kernel block

typedef __bf16 bf16x8 __attribute__((ext_vector_type(8)));
typedef float  f32x4  __attribute__((ext_vector_type(4)));

__device__ __forceinline__ void gload16(const void* g, void* l) {
    __builtin_amdgcn_global_load_lds(
        (const __attribute__((address_space(1))) unsigned int*)g,
        (__attribute__((address_space(3))) unsigned int*)l, 16, 0, 0);
}

// Ring-3 LDS pipeline, 2 stages in flight, counted vmcnt (R4-validated).
#define PIPE_BODY(T, CBUF, SBUF, DOSTAGE, LAST)                         \
    do {                                                                \
        if (LAST) asm volatile("s_waitcnt vmcnt(0)" ::: "memory");      \
        else      asm volatile("s_waitcnt vmcnt(5)" ::: "memory");      \
        __builtin_amdgcn_s_barrier();                                   \
        if (DOSTAGE) STAGE((T) + 2, SBUF);                              \
        COMPUTE(CBUF);                                                  \
    } while (0)

#define RUN_PIPE()                                                      \
    STAGE(0, 0); STAGE(1, 1);                                           \
    for (int t2 = 0; t2 < 7; ++t2) {                                    \
        int t = 3 * t2;                                                 \
        PIPE_BODY(t,     0, 2, true, false);                            \
        PIPE_BODY(t + 1, 1, 0, true, false);                            \
        PIPE_BODY(t + 2, 2, 1, true, false);                            \
    }                                                                   \
    PIPE_BODY(21, 0, 2, true,  false);                                  \
    PIPE_BODY(22, 1, 0, false, false);                                  \
    PIPE_BODY(23, 2, 1, false, true);

// ---------------- conv1: GEMM + bias/ReLU/LayerNorm -> bf16 h1pad ----------
__global__ __launch_bounds__(256) void gemm1_ln_kernel(
    const __bf16* __restrict__ xpad,   // (B, 514, 256)
    const __bf16* __restrict__ bmat,   // (256, 768)
    const float* __restrict__ bias,
    const float* __restrict__ gamma,
    const float* __restrict__ beta,
    __bf16* __restrict__ dst)          // h1pad (B,514,256)
{
    __shared__ __align__(16) unsigned char ring[3 * BUFSZ];
    __shared__ float part[64 * 4 * 2];
    __shared__ float tot[64 * 2];
    const int tid = threadIdx.x, lane = tid & 63, wid = tid >> 6;
    const int p = lane & 15, q = lane >> 4;
    const int m0 = blockIdx.x * TILE_M;
    const int bb = m0 >> 9, t0 = m0 & 511;
    const __bf16* aBase = xpad + ((size_t)bb * TP_ + t0) * D_;

    f32x4 acc[4][4];
#pragma unroll
    for (int mf = 0; mf < 4; ++mf)
#pragma unroll
        for (int nf = 0; nf < 4; ++nf)
            acc[mf][nf] = (f32x4){0.f, 0.f, 0.f, 0.f};

    auto STAGE = [&](int kstep, int buf) {
        unsigned char* Ab = ring + buf * BUFSZ;
        {   // A: 64 rows x 32 bf16
            int r = tid >> 2, scb = (tid & 3) ^ (r & 3);
            int k = kstep >> 3, i0 = (kstep & 7) * 32;
            gload16(aBase + (size_t)(r + k) * D_ + i0 + scb * 8, Ab + tid * 16);
        }
#pragma unroll
        for (int pp = 0; pp < 4; ++pp) {   // B: 256 rows x 32 bf16
            int c = pp * 256 + tid;
            int n = c >> 2, scb = (c & 3) ^ (n & 3);
            gload16(bmat + (size_t)n * KTOT + kstep * 32 + scb * 8,
                    Ab + 4096 + c * 16);
        }
    };
    auto COMPUTE = [&](int buf) {
        unsigned char* Ab = ring + buf * BUFSZ;
        unsigned char* Bb = Ab + 4096;
        const int rA = lane & 15;
        const int swz = (q ^ (rA & 3)) * 16;
        bf16x8 a[4], bv[4];
#pragma unroll
        for (int mf = 0; mf < 4; ++mf)
            a[mf] = *(const bf16x8*)(Ab + (mf * 16 + rA) * 64 + swz);
#pragma unroll
        for (int nf = 0; nf < 4; ++nf)
            bv[nf] = *(const bf16x8*)(Bb + (wid * 64 + nf * 16 + rA) * 64 + swz);
#pragma unroll
        for (int mf = 0; mf < 4; ++mf)
#pragma unroll
            for (int nf = 0; nf < 4; ++nf)
                acc[mf][nf] = __builtin_amdgcn_mfma_f32_16x16x32_bf16(
                    a[mf], bv[nf], acc[mf][nf], 0, 0, 0);
    };

    RUN_PIPE()

    float bcol[4], gcol[4], becol[4];
#pragma unroll
    for (int nf = 0; nf < 4; ++nf) {
        int c = wid * 64 + nf * 16 + p;
        bcol[nf] = bias[c]; gcol[nf] = gamma[c]; becol[nf] = beta[c];
    }
#pragma unroll
    for (int mf = 0; mf < 4; ++mf)
#pragma unroll
        for (int r = 0; r < 4; ++r) {
            float s = 0.f, s2 = 0.f;
#pragma unroll
            for (int nf = 0; nf < 4; ++nf) {
                float y = fmaxf(acc[mf][nf][r] + bcol[nf], 0.f);
                s += y; s2 += y * y;
            }
#pragma unroll
            for (int off = 8; off >= 1; off >>= 1) {
                s += __shfl_xor(s, off); s2 += __shfl_xor(s2, off);
            }
            if (p == 0) {
                int row = mf * 16 + q * 4 + r;
                part[(row * 4 + wid) * 2]     = s;
                part[(row * 4 + wid) * 2 + 1] = s2;
            }
        }
    __syncthreads();
    if (tid < 64) {
        float s = 0.f, s2 = 0.f;
#pragma unroll
        for (int w = 0; w < 4; ++w) {
            s  += part[(tid * 4 + w) * 2];
            s2 += part[(tid * 4 + w) * 2 + 1];
        }
        float m = s * (1.f / 256.f);
        float v = s2 * (1.f / 256.f) - m * m;
        tot[tid * 2]     = m;
        tot[tid * 2 + 1] = rsqrtf(v + 1e-5f);
    }
    __syncthreads();
#pragma unroll
    for (int mf = 0; mf < 4; ++mf)
#pragma unroll
        for (int r = 0; r < 4; ++r) {
            int row = mf * 16 + q * 4 + r;
            float m  = tot[row * 2];
            float rs = tot[row * 2 + 1];
            size_t gb = ((size_t)bb * TP_ + 1 + t0 + row) * D_;
#pragma unroll
            for (int nf = 0; nf < 4; ++nf) {
                int c = wid * 64 + nf * 16 + p;
                float y = fmaxf(acc[mf][nf][r] + bcol[nf], 0.f);
                dst[gb + c] = (__bf16)((y - m) * rs * gcol[nf] + becol[nf]);
            }
        }
}

// ---------------------------------------------------------------------------
// Merged kernel: blocks [0,256) = conv2 GEMM + fused LN+linear -> pred;
// blocks [256, ...) = gather, 32 output rows per block (4 waves x 8 rows,
// 4-deep load batching).  Overlaps compute-bound gemm2 with HBM-bound gather.
// ---------------------------------------------------------------------------
__global__ __launch_bounds__(256) void gemm2_gather_kernel(
    const __bf16* __restrict__ h1pad,  // (B, 514, 256)
    const __bf16* __restrict__ bmat,
    const float* __restrict__ bias,
    const float* __restrict__ gamma,
    const float* __restrict__ beta,
    const float* __restrict__ wl,
    const float* __restrict__ bl,
    const float* __restrict__ x,       // (B,512,256) fp32
    const int* __restrict__ ends,
    float* __restrict__ out,           // (B,maxLen,256)
    float* __restrict__ pred,          // (B, T)
    int maxLen)
{
    __shared__ __align__(16) unsigned char ring[3 * BUFSZ];
    __shared__ float part[64 * 4 * 4];
    __shared__ float sg[2];
    const int tid = threadIdx.x, lane = tid & 63, wid = tid >> 6;

    if (blockIdx.x >= 256) {
        // ---------------- gather part ----------------
        const int rowBase = (blockIdx.x - 256) * GROWS + wid * (GROWS / 4);
#pragma unroll
        for (int i = 0; i < GROWS / 4; i += 4) {
            const float* src[4];
            float4 v[4];
            int ok[4];
#pragma unroll
            for (int j = 0; j < 4; ++j) {
                int idx = rowBase + i + j;
                int b = idx / maxLen, m = idx - b * maxLen;
                ok[j] = (b < B_);
                src[j] = nullptr;
                if (ok[j]) {
                    const int* e = ends + b * T_;
                    if (m < e[T_ - 1]) {
                        int lo = 0, hi = T_ - 1;
                        while (lo < hi) {
                            int mid = (lo + hi) >> 1;
                            if (e[mid] > m) hi = mid; else lo = mid + 1;
                        }
                        src[j] = x + ((size_t)b * T_ + lo) * D_ + 4 * lane;
                    }
                }
            }
#pragma unroll
            for (int j = 0; j < 4; ++j)
                v[j] = src[j] ? *(const float4*)src[j]
                              : make_float4(0.f, 0.f, 0.f, 0.f);
#pragma unroll
            for (int j = 0; j < 4; ++j) {
                int idx = rowBase + i + j;
                if (ok[j])
                    *(float4*)(out + (size_t)idx * D_ + 4 * lane) = v[j];
            }
        }
        return;
    }

    // ---------------- gemm2 + pred part ----------------
    const int p = lane & 15, q = lane >> 4;
    const int m0 = blockIdx.x * TILE_M;
    const int bb = m0 >> 9, t0 = m0 & 511;
    if (tid < 64) {   // Sgw = sum g*wl, Sbw = sum be*wl + bl
        f32x4 g  = *(const f32x4*)(gamma + 4 * tid);
        f32x4 be = *(const f32x4*)(beta  + 4 * tid);
        f32x4 w  = *(const f32x4*)(wl    + 4 * tid);
        float a = g[0]*w[0] + g[1]*w[1] + g[2]*w[2] + g[3]*w[3];
        float b = be[0]*w[0] + be[1]*w[1] + be[2]*w[2] + be[3]*w[3];
#pragma unroll
        for (int off = 32; off >= 1; off >>= 1) {
            a += __shfl_xor(a, off); b += __shfl_xor(b, off);
        }
        if (tid == 0) { sg[0] = a; sg[1] = b + bl[0]; }
    }
    const __bf16* aBase = h1pad + ((size_t)bb * TP_ + t0) * D_;

    f32x4 acc[4][4];
#pragma unroll
    for (int mf = 0; mf < 4; ++mf)
#pragma unroll
        for (int nf = 0; nf < 4; ++nf)
            acc[mf][nf] = (f32x4){0.f, 0.f, 0.f, 0.f};

    auto STAGE = [&](int kstep, int buf) {
        unsigned char* Ab = ring + buf * BUFSZ;
        {   // A: 64 rows x 32 bf16
            int r = tid >> 2, scb = (tid & 3) ^ (r & 3);
            int k = kstep >> 3, i0 = (kstep & 7) * 32;
            gload16(aBase + (size_t)(r + k) * D_ + i0 + scb * 8, Ab + tid * 16);
        }
#pragma unroll
        for (int pp = 0; pp < 4; ++pp) {  // B: 256 rows x 32 bf16
            int c = pp * 256 + tid;
            int n = c >> 2, scb = (c & 3) ^ (n & 3);
            gload16(bmat + (size_t)n * KTOT + kstep * 32 + scb * 8,
                    Ab + 4096 + c * 16);
        }
    };
    auto COMPUTE = [&](int buf) {
        unsigned char* Ab = ring + buf * BUFSZ;
        unsigned char* Bb = Ab + 4096;
        const int rA = lane & 15;
        const int swz = (q ^ (rA & 3)) * 16;
        bf16x8 a[4], bv[4];
#pragma unroll
        for (int mf = 0; mf < 4; ++mf)
            a[mf] = *(const bf16x8*)(Ab + (mf * 16 + rA) * 64 + swz);
#pragma unroll
        for (int nf = 0; nf < 4; ++nf)
            bv[nf] = *(const bf16x8*)(Bb + (wid * 64 + nf * 16 + rA) * 64 + swz);
#pragma unroll
        for (int mf = 0; mf < 4; ++mf)
#pragma unroll
            for (int nf = 0; nf < 4; ++nf)
                acc[mf][nf] = __builtin_amdgcn_mfma_f32_16x16x32_bf16(
                    a[mf], bv[nf], acc[mf][nf], 0, 0, 0);
    };

    RUN_PIPE()

    float bcol[4], gwcol[4];
#pragma unroll
    for (int nf = 0; nf < 4; ++nf) {
        int c = wid * 64 + nf * 16 + p;
        bcol[nf]  = bias[c];
        gwcol[nf] = gamma[c] * wl[c];
    }
#pragma unroll
    for (int mf = 0; mf < 4; ++mf)
#pragma unroll
        for (int r = 0; r < 4; ++r) {
            float s = 0.f, s2 = 0.f, s3 = 0.f;
#pragma unroll
            for (int nf = 0; nf < 4; ++nf) {
                float y = fmaxf(acc[mf][nf][r] + bcol[nf], 0.f);
                s += y; s2 += y * y; s3 += y * gwcol[nf];
            }
#pragma unroll
            for (int off = 8; off >= 1; off >>= 1) {
                s  += __shfl_xor(s, off);
                s2 += __shfl_xor(s2, off);
                s3 += __shfl_xor(s3, off);
            }
            if (p == 0) {
                int row = mf * 16 + q * 4 + r;
                part[(row * 4 + wid) * 4]     = s;
                part[(row * 4 + wid) * 4 + 1] = s2;
                part[(row * 4 + wid) * 4 + 2] = s3;
            }
        }
    __syncthreads();
    if (tid < 64) {
        float s = 0.f, s2 = 0.f, s3 = 0.f;
#pragma unroll
        for (int w = 0; w < 4; ++w) {
            s  += part[(tid * 4 + w) * 4];
            s2 += part[(tid * 4 + w) * 4 + 1];
            s3 += part[(tid * 4 + w) * 4 + 2];
        }
        float m  = s * (1.f / 256.f);
        float v  = s2 * (1.f / 256.f) - m * m;
        float rs = rsqrtf(v + 1e-5f);
        pred[bb * T_ + t0 + tid] = rs * (s3 - m * sg[0]) + sg[1];
    }
}

// prep: scan (blocks 0..31) + bf16 xpad + weight transpose + h1pad pad rows.
__global__ __launch_bounds__(512) void prep_kernel(
    const int* __restrict__ td, const float* __restrict__ x,
    const float* __restrict__ w1, const float* __restrict__ w2,
    int* __restrict__ ends, __bf16* __restrict__ xpad,
    __bf16* __restrict__ bm1, __bf16* __restrict__ bm2,
    __bf16* __restrict__ h1pad)
{
    if (blockIdx.x < 32) {   // inclusive cumsum per batch
        __shared__ int s[T_];
        int b = blockIdx.x, t = threadIdx.x;
        s[t] = td[b * T_ + t];
        __syncthreads();
        for (int off = 1; off < T_; off <<= 1) {
            int add = (t >= off) ? s[t - off] : 0;
            __syncthreads();
            s[t] += add;
            __syncthreads();
        }
        ends[b * T_ + t] = s[t];
        return;
    }
    const int NX8 = B_ * TP_ * D_ / 8;   // 526,336
    const int NW8 = D_ * KTOT / 8;       // 24,576 per conv
    const int NZ8 = B_ * 2 * D_ / 8;     // 2,048
    int idx = (blockIdx.x - 32) * 512 + threadIdx.x;
    if (idx < NX8) {
        int e = idx * 8;
        int b = e / (TP_ * D_);
        int rem = e - b * (TP_ * D_);
        int r = rem >> 8, d = rem & 255;
        int t = r - 1;
        bf16x8 o;
        if ((unsigned)t < (unsigned)T_) {
            const float* xp = x + ((size_t)b * T_ + t) * D_ + d;
            f32x4 v0 = *(const f32x4*)xp;
            f32x4 v1 = *(const f32x4*)(xp + 4);
#pragma unroll
            for (int u = 0; u < 4; ++u) { o[u] = (__bf16)v0[u]; o[u+4] = (__bf16)v1[u]; }
        } else {
#pragma unroll
            for (int u = 0; u < 8; ++u) o[u] = (__bf16)0.f;
        }
        *(bf16x8*)(xpad + e) = o;
    } else if (idx < NX8 + 2 * NW8) {
        int j = (idx - NX8) * 8;
        const float* ws = w1;
        __bf16* bm = bm1;
        if (j >= D_ * KTOT) { j -= D_ * KTOT; ws = w2; bm = bm2; }
        int n = j / KTOT;
        int kap = j - n * KTOT;
        int k = kap >> 8, i = kap & 255;
        bf16x8 o;
#pragma unroll
        for (int u = 0; u < 8; ++u)
            o[u] = (__bf16)ws[(n * D_ + i + u) * 3 + k];
        *(bf16x8*)(bm + n * KTOT + kap) = o;
    } else if (idx < NX8 + 2 * NW8 + NZ8) {
        int j = (idx - NX8 - 2 * NW8) * 8;
        int b = j >> 9, qq = (j >> 8) & 1, d = j & 255;
        bf16x8 o;
#pragma unroll
        for (int u = 0; u < 8; ++u) o[u] = (__bf16)0.f;
        *(bf16x8*)(h1pad + ((size_t)b * TP_ + (qq ? TP_ - 1 : 0)) * D_ + d) = o;
    }
}

// Standalone gather (fallback when scratch is parked in d_out).
__global__ __launch_bounds__(256) void gather_kernel(
    const float* __restrict__ x, const int* __restrict__ ends,
    float* __restrict__ out, int maxLen)
{
    int tid = threadIdx.x, wd = tid >> 6, lane = tid & 63;
    int idx = blockIdx.x * 4 + wd;
    int b = idx / maxLen, m = idx % maxLen;
    if (b >= B_) return;
    const int* e = &ends[b * T_];
    float4 r = make_float4(0.f, 0.f, 0.f, 0.f);
    if (m < e[T_ - 1]) {
        int lo = 0, hi = T_ - 1;
        while (lo < hi) {
            int mid = (lo + hi) >> 1;
            if (e[mid] > m) hi = mid; else lo = mid + 1;
        }
        r = *(const float4*)(&x[((size_t)b * T_ + lo) * D_ + 4 * lane]);
    }
    *(float4*)(&out[((size_t)b * maxLen + m) * D_ + 4 * lane]) = r;
}

extern "C" void kernel_launch(void* const* d_in, const int* in_sizes, int n_in,
                              void* d_out, int out_size, void* d_ws, size_t ws_size,
                              hipStream_t stream) {
    const float* x   = (const float*)d_in[0];
    const int*   td  = (const int*)d_in[1];
    const float* w1  = (const float*)d_in[2];
    const float* b1  = (const float*)d_in[3];
    const float* g1  = (const float*)d_in[4];
    const float* be1 = (const float*)d_in[5];
    const float* w2  = (const float*)d_in[6];
    const float* b2  = (const float*)d_in[7];
    const float* g2  = (const float*)d_in[8];
    const float* be2 = (const float*)d_in[9];
    const float* wl  = (const float*)d_in[10];
    const float* bl  = (const float*)d_in[11];
    float* outp = (float*)d_out;

    const int BT = B_ * T_;
    const int maxLen = (out_size - BT) / (B_ * D_);
    float* predp = outp + (size_t)B_ * maxLen * D_;

    const size_t SZ_ENDS = 65536;
    const size_t SZ_XPAD = (size_t)B_ * TP_ * D_ * 2;   // 8,421,376
    const size_t SZ_H1   = SZ_XPAD;
    const size_t SZ_BM   = (size_t)D_ * KTOT * 2;       // 393,216
    const size_t need = SZ_ENDS + SZ_XPAD + SZ_H1 + 2 * SZ_BM;

    int* endsp = (int*)d_ws;
    char* base;
    const bool inWs = (ws_size >= need);
    if (inWs) base = (char*)d_ws + SZ_ENDS;
    else      base = (char*)d_out;   // consumed before standalone gather overwrites

    __bf16* xpadp  = (__bf16*)(base);
    __bf16* h1padp = (__bf16*)(base + SZ_XPAD);
    __bf16* bm1p   = (__bf16*)(base + SZ_XPAD + SZ_H1);
    __bf16* bm2p   = (__bf16*)(base + SZ_XPAD + SZ_H1 + SZ_BM);

    const int NX8 = B_ * TP_ * D_ / 8, NW8 = D_ * KTOT / 8, NZ8 = B_ * 2 * D_ / 8;
    const int prepBlocks = 32 + (NX8 + 2 * NW8 + NZ8 + 511) / 512;

    prep_kernel<<<prepBlocks, 512, 0, stream>>>(td, x, w1, w2, endsp, xpadp,
                                                bm1p, bm2p, h1padp);
    gemm1_ln_kernel<<<BT / TILE_M, 256, 0, stream>>>(xpadp, bm1p, b1, g1, be1, h1padp);

    if (inWs) {
        const int gBlocks = (B_ * maxLen + GROWS - 1) / GROWS;
        gemm2_gather_kernel<<<256 + gBlocks, 256, 0, stream>>>(
            h1padp, bm2p, b2, g2, be2, wl, bl, x, endsp, outp, predp, maxLen);
    } else {
        gemm2_gather_kernel<<<256, 256, 0, stream>>>(
            h1padp, bm2p, b2, g2, be2, wl, bl, x, endsp, outp, predp, maxLen);
        gather_kernel<<<(B_ * maxLen + 3) / 4, 256, 0, stream>>>(x, endsp, outp, maxLen);
    }
}

// Round 10
// 73.787 us; speedup vs baseline: 1.3357x; 1.3357x over previous
//
#include <hip/hip_runtime.h>
#include <math.h>

#define B_ 32
#define T_ 512
#define D_ 256
#define KTOT 768             // 3 taps x 256 channels
#define NSTEP 24             // KTOT / 32
#define TILE_M 64
#define APITCH 264           // bf16 elems per A-LDS row (528B, breaks alignment)
#define BBUF 16384           // one B stage: 256 rows x 32 bf16

typedef __bf16 bf16x8 __attribute__((ext_vector_type(8)));
typedef __bf16 bf16x4 __attribute__((ext_vector_type(4)));
typedef float  f32x4  __attribute__((ext_vector_type(4)));

__device__ __forceinline__ void gload16(const void* g, void* l) {
    __builtin_amdgcn_global_load_lds(
        (const __attribute__((address_space(1))) unsigned int*)g,
        (__attribute__((address_space(3))) unsigned int*)l, 16, 0, 0);
}

// B ring-3 stage: 1024 chunks of 16B; 512 threads -> 2 loads/thread (uniform).
#define BSTAGE(kstep, buf)                                              \
    do {                                                                \
        _Pragma("unroll")                                               \
        for (int pp = 0; pp < 2; ++pp) {                                \
            int c = pp * 512 + tid;                                     \
            int n = c >> 2, scb = (c & 3) ^ (n & 3);                    \
            gload16(bmat + (size_t)n * KTOT + (kstep) * 32 + scb * 8,   \
                    Bring + (buf) * BBUF + c * 16);                     \
        }                                                               \
    } while (0)

// Main loop: depth-2 B prefetch, counted vmcnt(2), one barrier per step.
#define RUN_PIPE(COMPUTE)                                               \
    _Pragma("unroll")                                                   \
    for (int k = 0; k < NSTEP; ++k) {                                   \
        if (k < NSTEP - 1) asm volatile("s_waitcnt vmcnt(2)" ::: "memory"); \
        else               asm volatile("s_waitcnt vmcnt(0)" ::: "memory"); \
        __builtin_amdgcn_s_barrier();                                   \
        if (k + 2 < NSTEP) BSTAGE(k + 2, (k + 2) % 3);                  \
        COMPUTE(k);                                                     \
    }

// ---------------------------------------------------------------------------
// conv1: A = 66 fp32 x-rows preloaded once -> bf16 LDS tile [66][264];
// per step only B is staged.  512 thr / 8 waves; wave = 64 rows x 32 cols
// (acc[4][2]).  Epilogue: bias/ReLU/LayerNorm -> bf16 h1pad rows 1..512.
// ---------------------------------------------------------------------------
__global__ __launch_bounds__(512) void gemm1_ln_kernel(
    const float* __restrict__ x,       // (B,512,256) fp32
    const __bf16* __restrict__ bmat,   // (256,768)
    const float* __restrict__ bias,
    const float* __restrict__ gamma,
    const float* __restrict__ beta,
    __bf16* __restrict__ dst)          // h1pad (B,514,256)
{
    __shared__ __align__(16) __bf16 Axs[66 * APITCH];
    __shared__ __align__(16) unsigned char Bring[3 * BBUF];
    __shared__ float part[64 * 8 * 2];
    __shared__ float tot[64 * 2];
    const int tid = threadIdx.x, lane = tid & 63, wid = tid >> 6;
    const int p = lane & 15, q = lane >> 4;
    const int m0 = blockIdx.x * TILE_M;
    const int bb = m0 >> 9, t0 = m0 & 511;
    const float* xb = x + (size_t)bb * T_ * D_;

    // ---- A preload: 4224 chunks of 4 f32 -> cvt -> 8B LDS write ----
#pragma unroll
    for (int i = 0; i < 9; ++i) {
        int c = tid + 512 * i;
        if (c < 4224) {
            int u = c >> 6, cf = c & 63;
            int t = t0 - 1 + u;
            bool v = ((unsigned)t < (unsigned)T_);
            f32x4 xv = *(const f32x4*)(xb + (size_t)(v ? t : 0) * D_ + cf * 4);
            bf16x4 o;
#pragma unroll
            for (int e = 0; e < 4; ++e) o[e] = (__bf16)(v ? xv[e] : 0.f);
            *(bf16x4*)(&Axs[u * APITCH + cf * 4]) = o;
        }
    }
    BSTAGE(0, 0); BSTAGE(1, 1);
    __syncthreads();   // drains A-writes + B stages 0,1 (prologue only)

    f32x4 acc[4][2];
#pragma unroll
    for (int mf = 0; mf < 4; ++mf)
#pragma unroll
        for (int nf = 0; nf < 2; ++nf)
            acc[mf][nf] = (f32x4){0.f, 0.f, 0.f, 0.f};

    auto COMPUTE = [&](int kstep) {
        const int tap = kstep >> 3;
        const int co = (kstep & 7) * 64;   // byte col offset within A row
        const unsigned char* Ab = (const unsigned char*)Axs;
        unsigned char* Bb = Bring + (kstep % 3) * BBUF;
        const int swz = (q ^ (p & 3)) * 16;
        bf16x8 a[4], bv[2];
#pragma unroll
        for (int mf = 0; mf < 4; ++mf)
            a[mf] = *(const bf16x8*)(Ab + (mf * 16 + p + tap) * (APITCH * 2)
                                     + co + q * 16);
#pragma unroll
        for (int nf = 0; nf < 2; ++nf)
            bv[nf] = *(const bf16x8*)(Bb + (wid * 32 + nf * 16 + p) * 64 + swz);
#pragma unroll
        for (int mf = 0; mf < 4; ++mf)
#pragma unroll
            for (int nf = 0; nf < 2; ++nf)
                acc[mf][nf] = __builtin_amdgcn_mfma_f32_16x16x32_bf16(
                    a[mf], bv[nf], acc[mf][nf], 0, 0, 0);
    };

    RUN_PIPE(COMPUTE)

    // ---- epilogue: bias+ReLU -> cross-wave LN -> bf16 h1pad ----
    float bcol[2], gcol[2], becol[2];
#pragma unroll
    for (int nf = 0; nf < 2; ++nf) {
        int c = wid * 32 + nf * 16 + p;
        bcol[nf] = bias[c]; gcol[nf] = gamma[c]; becol[nf] = beta[c];
    }
#pragma unroll
    for (int mf = 0; mf < 4; ++mf)
#pragma unroll
        for (int r = 0; r < 4; ++r) {
            float s = 0.f, s2 = 0.f;
#pragma unroll
            for (int nf = 0; nf < 2; ++nf) {
                float y = fmaxf(acc[mf][nf][r] + bcol[nf], 0.f);
                s += y; s2 += y * y;
            }
#pragma unroll
            for (int off = 8; off >= 1; off >>= 1) {
                s += __shfl_xor(s, off); s2 += __shfl_xor(s2, off);
            }
            if (p == 0) {
                int row = mf * 16 + q * 4 + r;
                part[(row * 8 + wid) * 2]     = s;
                part[(row * 8 + wid) * 2 + 1] = s2;
            }
        }
    __syncthreads();
    if (tid < 64) {
        float s = 0.f, s2 = 0.f;
#pragma unroll
        for (int w = 0; w < 8; ++w) {
            s  += part[(tid * 8 + w) * 2];
            s2 += part[(tid * 8 + w) * 2 + 1];
        }
        float m = s * (1.f / 256.f);
        float v = s2 * (1.f / 256.f) - m * m;
        tot[tid * 2]     = m;
        tot[tid * 2 + 1] = rsqrtf(v + 1e-5f);
    }
    __syncthreads();
#pragma unroll
    for (int mf = 0; mf < 4; ++mf)
#pragma unroll
        for (int r = 0; r < 4; ++r) {
            int row = mf * 16 + q * 4 + r;
            float m  = tot[row * 2];
            float rs = tot[row * 2 + 1];
            size_t gb = ((size_t)bb * (T_ + 2) + 1 + t0 + row) * D_;
#pragma unroll
            for (int nf = 0; nf < 2; ++nf) {
                int c = wid * 32 + nf * 16 + p;
                float y = fmaxf(acc[mf][nf][r] + bcol[nf], 0.f);
                dst[gb + c] = (__bf16)((y - m) * rs * gcol[nf] + becol[nf]);
            }
        }
}

// ---------------------------------------------------------------------------
// conv2: A = 66 bf16 h1pad rows preloaded once to [66][264]; B ring-staged.
// Epilogue folds LN + (h@wl+bl): pred = rstd*(S3 - mean*Sgw) + Sbw.
// ---------------------------------------------------------------------------
__global__ __launch_bounds__(512) void gemm2_pred_kernel(
    const __bf16* __restrict__ h1pad,  // (B, 514, 256)
    const __bf16* __restrict__ bmat,
    const float* __restrict__ bias,
    const float* __restrict__ gamma,
    const float* __restrict__ beta,
    const float* __restrict__ wl,
    const float* __restrict__ bl,
    float* __restrict__ pred)          // (B, T)
{
    __shared__ __align__(16) __bf16 Axs[66 * APITCH];
    __shared__ __align__(16) unsigned char Bring[3 * BBUF];
    __shared__ float part[64 * 8 * 4];
    __shared__ float sg[2];
    const int tid = threadIdx.x, lane = tid & 63, wid = tid >> 6;
    const int p = lane & 15, q = lane >> 4;
    const int m0 = blockIdx.x * TILE_M;
    const int bb = m0 >> 9, t0 = m0 & 511;

    if (tid < 64) {   // Sgw = sum g*wl, Sbw = sum be*wl + bl
        f32x4 g  = *(const f32x4*)(gamma + 4 * tid);
        f32x4 be = *(const f32x4*)(beta  + 4 * tid);
        f32x4 w  = *(const f32x4*)(wl    + 4 * tid);
        float a = g[0]*w[0] + g[1]*w[1] + g[2]*w[2] + g[3]*w[3];
        float b = be[0]*w[0] + be[1]*w[1] + be[2]*w[2] + be[3]*w[3];
#pragma unroll
        for (int off = 32; off >= 1; off >>= 1) {
            a += __shfl_xor(a, off); b += __shfl_xor(b, off);
        }
        if (tid == 0) { sg[0] = a; sg[1] = b + bl[0]; }
    }

    // ---- A preload: 2112 chunks of 16B bf16 (h1pad rows t0 .. t0+65) ----
    const __bf16* hb = h1pad + ((size_t)bb * (T_ + 2) + t0) * D_;
#pragma unroll
    for (int i = 0; i < 5; ++i) {
        int c = tid + 512 * i;
        if (c < 2112) {
            int u = c >> 5, off = c & 31;
            bf16x8 v = *(const bf16x8*)(hb + (size_t)u * D_ + off * 8);
            *(bf16x8*)(&Axs[u * APITCH + off * 8]) = v;
        }
    }
    BSTAGE(0, 0); BSTAGE(1, 1);
    __syncthreads();

    f32x4 acc[4][2];
#pragma unroll
    for (int mf = 0; mf < 4; ++mf)
#pragma unroll
        for (int nf = 0; nf < 2; ++nf)
            acc[mf][nf] = (f32x4){0.f, 0.f, 0.f, 0.f};

    auto COMPUTE = [&](int kstep) {
        const int tap = kstep >> 3;
        const int co = (kstep & 7) * 64;
        const unsigned char* Ab = (const unsigned char*)Axs;
        unsigned char* Bb = Bring + (kstep % 3) * BBUF;
        const int swz = (q ^ (p & 3)) * 16;
        bf16x8 a[4], bv[2];
#pragma unroll
        for (int mf = 0; mf < 4; ++mf)
            a[mf] = *(const bf16x8*)(Ab + (mf * 16 + p + tap) * (APITCH * 2)
                                     + co + q * 16);
#pragma unroll
        for (int nf = 0; nf < 2; ++nf)
            bv[nf] = *(const bf16x8*)(Bb + (wid * 32 + nf * 16 + p) * 64 + swz);
#pragma unroll
        for (int mf = 0; mf < 4; ++mf)
#pragma unroll
            for (int nf = 0; nf < 2; ++nf)
                acc[mf][nf] = __builtin_amdgcn_mfma_f32_16x16x32_bf16(
                    a[mf], bv[nf], acc[mf][nf], 0, 0, 0);
    };

    RUN_PIPE(COMPUTE)

    float bcol[2], gwcol[2];
#pragma unroll
    for (int nf = 0; nf < 2; ++nf) {
        int c = wid * 32 + nf * 16 + p;
        bcol[nf]  = bias[c];
        gwcol[nf] = gamma[c] * wl[c];
    }
#pragma unroll
    for (int mf = 0; mf < 4; ++mf)
#pragma unroll
        for (int r = 0; r < 4; ++r) {
            float s = 0.f, s2 = 0.f, s3 = 0.f;
#pragma unroll
            for (int nf = 0; nf < 2; ++nf) {
                float y = fmaxf(acc[mf][nf][r] + bcol[nf], 0.f);
                s += y; s2 += y * y; s3 += y * gwcol[nf];
            }
#pragma unroll
            for (int off = 8; off >= 1; off >>= 1) {
                s  += __shfl_xor(s, off);
                s2 += __shfl_xor(s2, off);
                s3 += __shfl_xor(s3, off);
            }
            if (p == 0) {
                int row = mf * 16 + q * 4 + r;
                part[(row * 8 + wid) * 4]     = s;
                part[(row * 8 + wid) * 4 + 1] = s2;
                part[(row * 8 + wid) * 4 + 2] = s3;
            }
        }
    __syncthreads();
    if (tid < 64) {
        float s = 0.f, s2 = 0.f, s3 = 0.f;
#pragma unroll
        for (int w = 0; w < 8; ++w) {
            s  += part[(tid * 8 + w) * 4];
            s2 += part[(tid * 8 + w) * 4 + 1];
            s3 += part[(tid * 8 + w) * 4 + 2];
        }
        float m  = s * (1.f / 256.f);
        float v  = s2 * (1.f / 256.f) - m * m;
        float rs = rsqrtf(v + 1e-5f);
        pred[bb * T_ + t0 + tid] = rs * (s3 - m * sg[0]) + sg[1];
    }
}

// prep: scan (blocks 0..31) + weight transpose + h1pad halo rows.
__global__ __launch_bounds__(512) void prep_kernel(
    const int* __restrict__ td, const float* __restrict__ w1,
    const float* __restrict__ w2,
    int* __restrict__ ends,
    __bf16* __restrict__ bm1, __bf16* __restrict__ bm2,
    __bf16* __restrict__ h1pad)
{
    if (blockIdx.x < 32) {   // inclusive cumsum per batch
        __shared__ int s[T_];
        int b = blockIdx.x, t = threadIdx.x;
        s[t] = td[b * T_ + t];
        __syncthreads();
        for (int off = 1; off < T_; off <<= 1) {
            int add = (t >= off) ? s[t - off] : 0;
            __syncthreads();
            s[t] += add;
            __syncthreads();
        }
        ends[b * T_ + t] = s[t];
        return;
    }
    const int NW8 = D_ * KTOT / 8;       // 24,576 per conv
    const int NZ8 = B_ * 2 * D_ / 8;     // 2,048
    int idx = (blockIdx.x - 32) * 512 + threadIdx.x;
    if (idx < 2 * NW8) {
        int j = idx * 8;
        const float* ws = w1;
        __bf16* bm = bm1;
        if (j >= D_ * KTOT) { j -= D_ * KTOT; ws = w2; bm = bm2; }
        int n = j / KTOT;
        int kap = j - n * KTOT;
        int k = kap >> 8, i = kap & 255;
        bf16x8 o;
#pragma unroll
        for (int u = 0; u < 8; ++u)
            o[u] = (__bf16)ws[(n * D_ + i + u) * 3 + k];
        *(bf16x8*)(bm + n * KTOT + kap) = o;
    } else if (idx < 2 * NW8 + NZ8) {
        int j = (idx - 2 * NW8) * 8;
        int b = j >> 9, qq = (j >> 8) & 1, d = j & 255;
        bf16x8 o;
#pragma unroll
        for (int u = 0; u < 8; ++u) o[u] = (__bf16)0.f;
        *(bf16x8*)(h1pad + ((size_t)b * (T_ + 2) + (qq ? T_ + 1 : 0)) * D_ + d) = o;
    }
}

// out[b,m,:] = x[b, t(m), :] via binary search over ends; zeros past lens[b].
__global__ __launch_bounds__(256) void gather_kernel(
    const float* __restrict__ x, const int* __restrict__ ends,
    float* __restrict__ out, int maxLen)
{
    int tid = threadIdx.x, wd = tid >> 6, lane = tid & 63;
    int idx = blockIdx.x * 4 + wd;
    int b = idx / maxLen, m = idx % maxLen;
    if (b >= B_) return;
    const int* e = &ends[b * T_];
    float4 r = make_float4(0.f, 0.f, 0.f, 0.f);
    if (m < e[T_ - 1]) {
        int lo = 0, hi = T_ - 1;
        while (lo < hi) {
            int mid = (lo + hi) >> 1;
            if (e[mid] > m) hi = mid; else lo = mid + 1;
        }
        r = *(const float4*)(&x[((size_t)b * T_ + lo) * D_ + 4 * lane]);
    }
    *(float4*)(&out[((size_t)b * maxLen + m) * D_ + 4 * lane]) = r;
}

extern "C" void kernel_launch(void* const* d_in, const int* in_sizes, int n_in,
                              void* d_out, int out_size, void* d_ws, size_t ws_size,
                              hipStream_t stream) {
    const float* x   = (const float*)d_in[0];
    const int*   td  = (const int*)d_in[1];
    const float* w1  = (const float*)d_in[2];
    const float* b1  = (const float*)d_in[3];
    const float* g1  = (const float*)d_in[4];
    const float* be1 = (const float*)d_in[5];
    const float* w2  = (const float*)d_in[6];
    const float* b2  = (const float*)d_in[7];
    const float* g2  = (const float*)d_in[8];
    const float* be2 = (const float*)d_in[9];
    const float* wl  = (const float*)d_in[10];
    const float* bl  = (const float*)d_in[11];
    float* outp = (float*)d_out;

    const int BT = B_ * T_;
    const int maxLen = (out_size - BT) / (B_ * D_);
    float* predp = outp + (size_t)B_ * maxLen * D_;

    const size_t SZ_ENDS = 65536;
    const size_t SZ_H1   = (size_t)B_ * (T_ + 2) * D_ * 2;  // 8,421,376
    const size_t SZ_BM   = (size_t)D_ * KTOT * 2;           // 393,216
    const size_t need = SZ_ENDS + SZ_H1 + 2 * SZ_BM;

    int* endsp = (int*)d_ws;
    char* base;
    if (ws_size >= need) base = (char*)d_ws + SZ_ENDS;
    else                 base = (char*)d_out;  // consumed before gather overwrites

    __bf16* h1padp = (__bf16*)(base);
    __bf16* bm1p   = (__bf16*)(base + SZ_H1);
    __bf16* bm2p   = (__bf16*)(base + SZ_H1 + SZ_BM);

    const int NW8 = D_ * KTOT / 8, NZ8 = B_ * 2 * D_ / 8;
    const int prepBlocks = 32 + (2 * NW8 + NZ8 + 511) / 512;

    prep_kernel<<<prepBlocks, 512, 0, stream>>>(td, w1, w2, endsp, bm1p, bm2p, h1padp);
    gemm1_ln_kernel<<<BT / TILE_M, 512, 0, stream>>>(x, bm1p, b1, g1, be1, h1padp);
    gemm2_pred_kernel<<<BT / TILE_M, 512, 0, stream>>>(h1padp, bm2p, b2, g2, be2,
                                                       wl, bl, predp);
    gather_kernel<<<(B_ * maxLen + 3) / 4, 256, 0, stream>>>(x, endsp, outp, maxLen);
}